// Round 1
// baseline (236.151 us; speedup 1.0000x reference)
//
#include <hip/hip_runtime.h>
#include <cmath>

namespace {

constexpr int BATCH = 256;
// layer 1
constexpr int C1 = 3, H1 = 218, W1 = 178;
constexpr int IMG1 = C1 * H1 * W1;            // 116412
constexpr int PLANE1 = H1 * W1;               // 38804
constexpr int O1 = 8, HO1 = 54, WO1 = 44;
constexpr int HW1 = HO1 * WO1;                // 2376
constexpr int P1 = C1 * 36;                   // 108
// layer 2
constexpr int C2 = 8, H2c = 54, W2c = 44;
constexpr int IMG2 = C2 * H2c * W2c;          // 19008
constexpr int PLANE2 = H2c * W2c;             // 2376
constexpr int O2 = 16, HO2 = 13, WO2 = 10;
constexpr int HW2 = HO2 * WO2;                // 130
constexpr int P2 = C2 * 36;                   // 288
// head
constexpr int NPOOL = 480;                    // 16*6*5
constexpr int N1 = 300, N2 = 200;

// ---- transpose w1 (O1,P1,HW1) -> (P1*HW1, O1) so each lane reads 8 contiguous floats
__global__ __launch_bounds__(256) void wt1_kernel(const float* __restrict__ w,
                                                  float* __restrict__ wt) {
  const int idx = blockIdx.x * 256 + threadIdx.x;   // p*HW1 + hw
  if (idx >= P1 * HW1) return;
  float v[O1];
#pragma unroll
  for (int o = 0; o < O1; ++o) v[o] = w[(size_t)o * (P1 * HW1) + idx];
  float4* dst = reinterpret_cast<float4*>(wt + (size_t)idx * O1);
  dst[0] = make_float4(v[0], v[1], v[2], v[3]);
  dst[1] = make_float4(v[4], v[5], v[6], v[7]);
}

// ---- transpose w2 (O2,P2,HW2) -> (P2*HW2, O2)
__global__ __launch_bounds__(256) void wt2_kernel(const float* __restrict__ w,
                                                  float* __restrict__ wt) {
  const int idx = blockIdx.x * 256 + threadIdx.x;   // p*HW2 + hw
  if (idx >= P2 * HW2) return;
  float v[O2];
#pragma unroll
  for (int o = 0; o < O2; ++o) v[o] = w[(size_t)o * (P2 * HW2) + idx];
  float4* dst = reinterpret_cast<float4*>(wt + (size_t)idx * O2);
  dst[0] = make_float4(v[0], v[1], v[2], v[3]);
  dst[1] = make_float4(v[4], v[5], v[6], v[7]);
  dst[2] = make_float4(v[8], v[9], v[10], v[11]);
  dst[3] = make_float4(v[12], v[13], v[14], v[15]);
}

// ---- locally-connected layer 1 + ReLU
// grid (BATCH/4, ceil(HW1/256)); thread owns one hw location x 4 batch x 8 out-ch
__global__ __launch_bounds__(256) void lc1_kernel(const float* __restrict__ x,
                                                  const float* __restrict__ w1t,
                                                  const float* __restrict__ b1,
                                                  float* __restrict__ h1) {
  const int hw = blockIdx.y * 256 + threadIdx.x;
  if (hw >= HW1) return;
  const int bg = blockIdx.x * 4;
  const int ho = hw / WO1, wo = hw - ho * WO1;

  float acc[4][O1];
#pragma unroll
  for (int o = 0; o < O1; ++o) {
    const float bv = b1[o * HW1 + hw];
#pragma unroll
    for (int j = 0; j < 4; ++j) acc[j][o] = bv;
  }

  const float* xbase = x + (size_t)bg * IMG1 + (size_t)(ho * 4) * W1 + wo * 4;
  const float* wbase = w1t + (size_t)hw * O1;

#pragma unroll 1
  for (int c = 0; c < C1; ++c) {
#pragma unroll
    for (int kh = 0; kh < 6; ++kh) {
      float xv[4][6];
#pragma unroll
      for (int j = 0; j < 4; ++j) {
        const float* xr = xbase + (size_t)j * IMG1 + c * PLANE1 + kh * W1;
        const float2 a0 = *reinterpret_cast<const float2*>(xr);
        const float2 a1 = *reinterpret_cast<const float2*>(xr + 2);
        const float2 a2 = *reinterpret_cast<const float2*>(xr + 4);
        xv[j][0] = a0.x; xv[j][1] = a0.y;
        xv[j][2] = a1.x; xv[j][3] = a1.y;
        xv[j][4] = a2.x; xv[j][5] = a2.y;
      }
#pragma unroll
      for (int kw = 0; kw < 6; ++kw) {
        const int p = (c * 6 + kh) * 6 + kw;
        const float4 wa = *reinterpret_cast<const float4*>(wbase + (size_t)p * (HW1 * O1));
        const float4 wb = *reinterpret_cast<const float4*>(wbase + (size_t)p * (HW1 * O1) + 4);
#pragma unroll
        for (int j = 0; j < 4; ++j) {
          const float xs = xv[j][kw];
          acc[j][0] = fmaf(xs, wa.x, acc[j][0]);
          acc[j][1] = fmaf(xs, wa.y, acc[j][1]);
          acc[j][2] = fmaf(xs, wa.z, acc[j][2]);
          acc[j][3] = fmaf(xs, wa.w, acc[j][3]);
          acc[j][4] = fmaf(xs, wb.x, acc[j][4]);
          acc[j][5] = fmaf(xs, wb.y, acc[j][5]);
          acc[j][6] = fmaf(xs, wb.z, acc[j][6]);
          acc[j][7] = fmaf(xs, wb.w, acc[j][7]);
        }
      }
    }
  }

#pragma unroll
  for (int j = 0; j < 4; ++j) {
    float* op = h1 + ((size_t)(bg + j) * O1) * HW1 + hw;
#pragma unroll
    for (int o = 0; o < O1; ++o) op[(size_t)o * HW1] = fmaxf(acc[j][o], 0.f);
  }
}

// ---- locally-connected layer 2 + ReLU
// grid (BATCH/2, 2): thread owns one hw (of 130) x 2 batch x 8 out-ch (o-half by blockIdx.y)
__global__ __launch_bounds__(256) void lc2_kernel(const float* __restrict__ h1,
                                                  const float* __restrict__ w2t,
                                                  const float* __restrict__ b2,
                                                  float* __restrict__ h2) {
  const int hw = threadIdx.x;
  if (hw >= HW2) return;
  const int bg = blockIdx.x * 2;
  const int oh = blockIdx.y * 8;
  const int ho = hw / WO2, wo = hw - ho * WO2;

  float acc[2][8];
#pragma unroll
  for (int o = 0; o < 8; ++o) {
    const float bv = b2[(oh + o) * HW2 + hw];
    acc[0][o] = bv;
    acc[1][o] = bv;
  }

  const float* xbase = h1 + (size_t)bg * IMG2 + (size_t)(ho * 4) * W2c + wo * 4;
  const float* wbase = w2t + (size_t)hw * O2 + oh;

#pragma unroll 1
  for (int c = 0; c < C2; ++c) {
#pragma unroll
    for (int kh = 0; kh < 6; ++kh) {
      float xv[2][6];
#pragma unroll
      for (int j = 0; j < 2; ++j) {
        const float* xr = xbase + (size_t)j * IMG2 + c * PLANE2 + kh * W2c;
        const float2 a0 = *reinterpret_cast<const float2*>(xr);
        const float2 a1 = *reinterpret_cast<const float2*>(xr + 2);
        const float2 a2 = *reinterpret_cast<const float2*>(xr + 4);
        xv[j][0] = a0.x; xv[j][1] = a0.y;
        xv[j][2] = a1.x; xv[j][3] = a1.y;
        xv[j][4] = a2.x; xv[j][5] = a2.y;
      }
#pragma unroll
      for (int kw = 0; kw < 6; ++kw) {
        const int p = (c * 6 + kh) * 6 + kw;
        const float4 wa = *reinterpret_cast<const float4*>(wbase + (size_t)p * (HW2 * O2));
        const float4 wb = *reinterpret_cast<const float4*>(wbase + (size_t)p * (HW2 * O2) + 4);
#pragma unroll
        for (int j = 0; j < 2; ++j) {
          const float xs = xv[j][kw];
          acc[j][0] = fmaf(xs, wa.x, acc[j][0]);
          acc[j][1] = fmaf(xs, wa.y, acc[j][1]);
          acc[j][2] = fmaf(xs, wa.z, acc[j][2]);
          acc[j][3] = fmaf(xs, wa.w, acc[j][3]);
          acc[j][4] = fmaf(xs, wb.x, acc[j][4]);
          acc[j][5] = fmaf(xs, wb.y, acc[j][5]);
          acc[j][6] = fmaf(xs, wb.z, acc[j][6]);
          acc[j][7] = fmaf(xs, wb.w, acc[j][7]);
        }
      }
    }
  }

#pragma unroll
  for (int j = 0; j < 2; ++j) {
#pragma unroll
    for (int o = 0; o < 8; ++o) {
      h2[((size_t)(bg + j) * O2 + oh + o) * HW2 + hw] = fmaxf(acc[j][o], 0.f);
    }
  }
}

// ---- maxpool 2x2 (floor) + flatten: h2 (B,16,13,10) -> pooled (B,480)
__global__ __launch_bounds__(256) void pool_kernel(const float* __restrict__ h2,
                                                   float* __restrict__ pooled) {
  const int idx = blockIdx.x * 256 + threadIdx.x;
  if (idx >= BATCH * NPOOL) return;
  const int b = idx / NPOOL, r = idx - b * NPOOL;
  const int o = r / 30, r2 = r - o * 30;
  const int i = r2 / 5, j = r2 - i * 5;
  const float* base = h2 + ((size_t)(b * O2 + o) * HO2 + 2 * i) * WO2 + 2 * j;
  const float m = fmaxf(fmaxf(base[0], base[1]), fmaxf(base[WO2], base[WO2 + 1]));
  pooled[idx] = m;
}

// ---- FC1 (480->300) + ReLU. One block per batch row; wave-per-neuron, shuffle reduce.
__global__ __launch_bounds__(256) void fc1_kernel(const float* __restrict__ pooled,
                                                  const float* __restrict__ w,
                                                  const float* __restrict__ bias,
                                                  float* __restrict__ h3) {
  __shared__ float sv[NPOOL];
  const int b = blockIdx.x;
  const int tid = threadIdx.x;
  const float* src = pooled + (size_t)b * NPOOL;
  sv[tid] = src[tid];
  if (tid < NPOOL - 256) sv[256 + tid] = src[256 + tid];
  __syncthreads();
  const int wave = tid >> 6, lane = tid & 63;
  for (int n = wave; n < N1; n += 4) {
    const float* wr = w + (size_t)n * NPOOL;
    float s = 0.f;
#pragma unroll
    for (int kk = 0; kk < 7; ++kk) {
      const int k = kk * 64 + lane;
      s = fmaf(wr[k], sv[k], s);
    }
    if (lane < NPOOL - 448) {
      const int k = 448 + lane;
      s = fmaf(wr[k], sv[k], s);
    }
#pragma unroll
    for (int off = 32; off > 0; off >>= 1) s += __shfl_xor(s, off, 64);
    if (lane == 0) h3[(size_t)b * N1 + n] = fmaxf(s + bias[n], 0.f);
  }
}

// ---- FC2 (300->200) + softmax. One block per batch row.
__global__ __launch_bounds__(256) void fc2sm_kernel(const float* __restrict__ h3,
                                                    const float* __restrict__ w,
                                                    const float* __restrict__ bias,
                                                    float* __restrict__ out) {
  __shared__ float sv[N1];
  __shared__ float sl[N2];
  __shared__ float sred;
  const int b = blockIdx.x;
  const int tid = threadIdx.x;
  const float* src = h3 + (size_t)b * N1;
  if (tid < N1) sv[tid] = src[tid];                 // tid<256 (<300) all valid
  if (tid < N1 - 256) sv[256 + tid] = src[256 + tid];
  __syncthreads();
  float e = 0.f;
  if (tid < N2) {
    const float* wr = w + (size_t)tid * N1;
    float s = bias[tid];
    for (int k = 0; k < N1; k += 2) {
      s = fmaf(wr[k], sv[k], s);
      s = fmaf(wr[k + 1], sv[k + 1], s);
    }
    sl[tid] = s;
  }
  __syncthreads();
  if (tid < 64) {
    float m = -INFINITY;
    for (int i = tid; i < N2; i += 64) m = fmaxf(m, sl[i]);
#pragma unroll
    for (int off = 32; off > 0; off >>= 1) m = fmaxf(m, __shfl_xor(m, off, 64));
    if (tid == 0) sred = m;
  }
  __syncthreads();
  const float mx = sred;
  if (tid < N2) {
    e = expf(sl[tid] - mx);
    sl[tid] = e;
  }
  __syncthreads();
  if (tid < 64) {
    float s = 0.f;
    for (int i = tid; i < N2; i += 64) s += sl[i];
#pragma unroll
    for (int off = 32; off > 0; off >>= 1) s += __shfl_xor(s, off, 64);
    if (tid == 0) sred = s;
  }
  __syncthreads();
  if (tid < N2) out[(size_t)b * N2 + tid] = e / sred;
}

}  // namespace

extern "C" void kernel_launch(void* const* d_in, const int* in_sizes, int n_in,
                              void* d_out, int out_size, void* d_ws, size_t ws_size,
                              hipStream_t stream) {
  const float* x     = (const float*)d_in[0];
  const float* w1    = (const float*)d_in[1];
  const float* b1    = (const float*)d_in[2];
  const float* w2    = (const float*)d_in[3];
  const float* b2    = (const float*)d_in[4];
  const float* fc1_w = (const float*)d_in[5];
  const float* fc1_b = (const float*)d_in[6];
  const float* fc2_w = (const float*)d_in[7];
  const float* fc2_b = (const float*)d_in[8];
  float* out = (float*)d_out;

  float* ws     = (float*)d_ws;
  float* w1t    = ws;                                  // 2,052,864 f
  float* w2t    = w1t + (size_t)O1 * P1 * HW1;         //   599,040 f
  float* h1     = w2t + (size_t)O2 * P2 * HW2;         // 4,866,048 f
  float* h2     = h1 + (size_t)BATCH * O1 * HW1;       //   532,480 f
  float* pooled = h2 + (size_t)BATCH * O2 * HW2;       //   122,880 f
  float* h3     = pooled + (size_t)BATCH * NPOOL;      //    76,800 f
  // total ~33 MB of d_ws

  wt1_kernel<<<(P1 * HW1 + 255) / 256, 256, 0, stream>>>(w1, w1t);
  wt2_kernel<<<(P2 * HW2 + 255) / 256, 256, 0, stream>>>(w2, w2t);
  lc1_kernel<<<dim3(BATCH / 4, (HW1 + 255) / 256), 256, 0, stream>>>(x, w1t, b1, h1);
  lc2_kernel<<<dim3(BATCH / 2, 2), 256, 0, stream>>>(h1, w2t, b2, h2);
  pool_kernel<<<(BATCH * NPOOL + 255) / 256, 256, 0, stream>>>(h2, pooled);
  fc1_kernel<<<BATCH, 256, 0, stream>>>(pooled, fc1_w, fc1_b, h3);
  fc2sm_kernel<<<BATCH, 256, 0, stream>>>(h3, fc2_w, fc2_b, out);
}

// Round 2
// 191.594 us; speedup vs baseline: 1.2326x; 1.2326x over previous
//
#include <hip/hip_runtime.h>
#include <cmath>

namespace {

constexpr int BATCH = 256;
// layer 1
constexpr int C1 = 3, H1 = 218, W1 = 178;
constexpr int IMG1 = C1 * H1 * W1;            // 116412
constexpr int PLANE1 = H1 * W1;               // 38804
constexpr int O1 = 8, HO1 = 54, WO1 = 44;
constexpr int HW1 = HO1 * WO1;                // 2376
constexpr int P1 = C1 * 36;                   // 108
// layer 2
constexpr int C2 = 8, H2c = 54, W2c = 44;
constexpr int IMG2 = C2 * H2c * W2c;          // 19008
constexpr int PLANE2 = H2c * W2c;             // 2376
constexpr int O2 = 16, HO2 = 13, WO2 = 10;
constexpr int HW2 = HO2 * WO2;                // 130
constexpr int P2 = C2 * 36;                   // 288
// head
constexpr int NPOOL = 480;                    // 16*6*5
constexpr int N1 = 300, N2 = 200;

// ---- transpose w1 (O1,P1,HW1) -> (P1*HW1, O1) so each lane reads 8 contiguous floats
__global__ __launch_bounds__(256) void wt1_kernel(const float* __restrict__ w,
                                                  float* __restrict__ wt) {
  const int idx = blockIdx.x * 256 + threadIdx.x;   // p*HW1 + hw
  if (idx >= P1 * HW1) return;
  float v[O1];
#pragma unroll
  for (int o = 0; o < O1; ++o) v[o] = w[(size_t)o * (P1 * HW1) + idx];
  float4* dst = reinterpret_cast<float4*>(wt + (size_t)idx * O1);
  dst[0] = make_float4(v[0], v[1], v[2], v[3]);
  dst[1] = make_float4(v[4], v[5], v[6], v[7]);
}

// ---- transpose w2 (O2,P2,HW2) -> (P2*HW2, O2)
__global__ __launch_bounds__(256) void wt2_kernel(const float* __restrict__ w,
                                                  float* __restrict__ wt) {
  const int idx = blockIdx.x * 256 + threadIdx.x;   // p*HW2 + hw
  if (idx >= P2 * HW2) return;
  float v[O2];
#pragma unroll
  for (int o = 0; o < O2; ++o) v[o] = w[(size_t)o * (P2 * HW2) + idx];
  float4* dst = reinterpret_cast<float4*>(wt + (size_t)idx * O2);
  dst[0] = make_float4(v[0], v[1], v[2], v[3]);
  dst[1] = make_float4(v[4], v[5], v[6], v[7]);
  dst[2] = make_float4(v[8], v[9], v[10], v[11]);
  dst[3] = make_float4(v[12], v[13], v[14], v[15]);
}

// ---- locally-connected layer 1 + ReLU
// block: 256 threads = 64 hw-lanes x 4 waves (each wave a batch-quad).
// grid (ceil(HW1/64)=38, 16): block covers 64 hw x 16 batches x 8 o.
// 4 waves share the same weight stream (L1 temporal reuse); only 16 blocks
// along batch re-read w1t from L2 (was 64).
__global__ __launch_bounds__(256) void lc1_kernel(const float* __restrict__ x,
                                                  const float* __restrict__ w1t,
                                                  const float* __restrict__ b1,
                                                  float* __restrict__ h1) {
  const int lane = threadIdx.x & 63;
  const int wave = threadIdx.x >> 6;
  const int hw = blockIdx.x * 64 + lane;
  if (hw >= HW1) return;
  const int bg = blockIdx.y * 16 + wave * 4;
  const int ho = hw / WO1, wo = hw - ho * WO1;

  float acc[4][O1];
#pragma unroll
  for (int o = 0; o < O1; ++o) {
    const float bv = b1[o * HW1 + hw];
#pragma unroll
    for (int j = 0; j < 4; ++j) acc[j][o] = bv;
  }

  const float* xbase = x + (size_t)bg * IMG1 + (size_t)(ho * 4) * W1 + wo * 4;
  const float* wbase = w1t + (size_t)hw * O1;

#pragma unroll 1
  for (int c = 0; c < C1; ++c) {
#pragma unroll
    for (int kh = 0; kh < 6; ++kh) {
      float xv[4][6];
#pragma unroll
      for (int j = 0; j < 4; ++j) {
        const float* xr = xbase + (size_t)j * IMG1 + c * PLANE1 + kh * W1;
        const float2 a0 = *reinterpret_cast<const float2*>(xr);
        const float2 a1 = *reinterpret_cast<const float2*>(xr + 2);
        const float2 a2 = *reinterpret_cast<const float2*>(xr + 4);
        xv[j][0] = a0.x; xv[j][1] = a0.y;
        xv[j][2] = a1.x; xv[j][3] = a1.y;
        xv[j][4] = a2.x; xv[j][5] = a2.y;
      }
#pragma unroll
      for (int kw = 0; kw < 6; ++kw) {
        const int p = (c * 6 + kh) * 6 + kw;
        const float4 wa = *reinterpret_cast<const float4*>(wbase + (size_t)p * (HW1 * O1));
        const float4 wb = *reinterpret_cast<const float4*>(wbase + (size_t)p * (HW1 * O1) + 4);
#pragma unroll
        for (int j = 0; j < 4; ++j) {
          const float xs = xv[j][kw];
          acc[j][0] = fmaf(xs, wa.x, acc[j][0]);
          acc[j][1] = fmaf(xs, wa.y, acc[j][1]);
          acc[j][2] = fmaf(xs, wa.z, acc[j][2]);
          acc[j][3] = fmaf(xs, wa.w, acc[j][3]);
          acc[j][4] = fmaf(xs, wb.x, acc[j][4]);
          acc[j][5] = fmaf(xs, wb.y, acc[j][5]);
          acc[j][6] = fmaf(xs, wb.z, acc[j][6]);
          acc[j][7] = fmaf(xs, wb.w, acc[j][7]);
        }
      }
    }
  }

#pragma unroll
  for (int j = 0; j < 4; ++j) {
    float* op = h1 + ((size_t)(bg + j) * O1) * HW1 + hw;
#pragma unroll
    for (int o = 0; o < O1; ++o) op[(size_t)o * HW1] = fmaxf(acc[j][o], 0.f);
  }
}

// ---- locally-connected layer 2 + ReLU, GEMM-ified per spatial location.
// grid (HW2=130, 4 batch-quads); block 256 = 64 batch-lanes x 4 o-group waves.
// Per-hw weight slice (288x16 = 18.4 KB) staged in LDS once; inner loop is
// one broadcast ds_read_b128 + 4 FMAs per p per thread. All lanes active.
__global__ __launch_bounds__(256) void lc2_kernel(const float* __restrict__ h1,
                                                  const float* __restrict__ w2t,
                                                  const float* __restrict__ b2,
                                                  float* __restrict__ h2) {
  __shared__ float ws[P2 * O2];                 // 4608 floats = 18432 B
  const int hw = blockIdx.x;
  const int lane = threadIdx.x & 63;
  const int og = threadIdx.x >> 6;              // o-group: 4 outputs
  const int b = blockIdx.y * 64 + lane;
  const int ho = hw / WO2, wo = hw - ho * WO2;

  // cooperative stage of weights for this hw: ws[p*16+o]
  for (int i = threadIdx.x; i < P2 * O2; i += 256) {
    const int p = i >> 4, o = i & 15;
    ws[i] = w2t[((size_t)p * HW2 + hw) * O2 + o];
  }
  __syncthreads();

  float acc[4];
#pragma unroll
  for (int oi = 0; oi < 4; ++oi) acc[oi] = b2[(og * 4 + oi) * HW2 + hw];

  const float* xb = h1 + (size_t)b * IMG2 + (size_t)(ho * 4) * W2c + wo * 4;

#pragma unroll 1
  for (int c = 0; c < C2; ++c) {
#pragma unroll
    for (int kh = 0; kh < 6; ++kh) {
      const float* xr = xb + c * PLANE2 + kh * W2c;
      const float2 a0 = *reinterpret_cast<const float2*>(xr);
      const float2 a1 = *reinterpret_cast<const float2*>(xr + 2);
      const float2 a2 = *reinterpret_cast<const float2*>(xr + 4);
      float xv[6];
      xv[0] = a0.x; xv[1] = a0.y; xv[2] = a1.x;
      xv[3] = a1.y; xv[4] = a2.x; xv[5] = a2.y;
#pragma unroll
      for (int kw = 0; kw < 6; ++kw) {
        const int p = (c * 6 + kh) * 6 + kw;
        const float4 wv = *reinterpret_cast<const float4*>(&ws[p * O2 + og * 4]);
        acc[0] = fmaf(xv[kw], wv.x, acc[0]);
        acc[1] = fmaf(xv[kw], wv.y, acc[1]);
        acc[2] = fmaf(xv[kw], wv.z, acc[2]);
        acc[3] = fmaf(xv[kw], wv.w, acc[3]);
      }
    }
  }

#pragma unroll
  for (int oi = 0; oi < 4; ++oi) {
    h2[((size_t)b * O2 + og * 4 + oi) * HW2 + hw] = fmaxf(acc[oi], 0.f);
  }
}

// ---- maxpool 2x2 (floor) + flatten: h2 (B,16,13,10) -> pooled (B,480)
__global__ __launch_bounds__(256) void pool_kernel(const float* __restrict__ h2,
                                                   float* __restrict__ pooled) {
  const int idx = blockIdx.x * 256 + threadIdx.x;
  if (idx >= BATCH * NPOOL) return;
  const int b = idx / NPOOL, r = idx - b * NPOOL;
  const int o = r / 30, r2 = r - o * 30;
  const int i = r2 / 5, j = r2 - i * 5;
  const float* base = h2 + ((size_t)(b * O2 + o) * HO2 + 2 * i) * WO2 + 2 * j;
  const float m = fmaxf(fmaxf(base[0], base[1]), fmaxf(base[WO2], base[WO2 + 1]));
  pooled[idx] = m;
}

// ---- FC1 (480->300) + ReLU. One block per batch row; wave-per-neuron, shuffle reduce.
__global__ __launch_bounds__(256) void fc1_kernel(const float* __restrict__ pooled,
                                                  const float* __restrict__ w,
                                                  const float* __restrict__ bias,
                                                  float* __restrict__ h3) {
  __shared__ float sv[NPOOL];
  const int b = blockIdx.x;
  const int tid = threadIdx.x;
  const float* src = pooled + (size_t)b * NPOOL;
  sv[tid] = src[tid];
  if (tid < NPOOL - 256) sv[256 + tid] = src[256 + tid];
  __syncthreads();
  const int wave = tid >> 6, lane = tid & 63;
  for (int n = wave; n < N1; n += 4) {
    const float* wr = w + (size_t)n * NPOOL;
    float s = 0.f;
#pragma unroll
    for (int kk = 0; kk < 7; ++kk) {
      const int k = kk * 64 + lane;
      s = fmaf(wr[k], sv[k], s);
    }
    if (lane < NPOOL - 448) {
      const int k = 448 + lane;
      s = fmaf(wr[k], sv[k], s);
    }
#pragma unroll
    for (int off = 32; off > 0; off >>= 1) s += __shfl_xor(s, off, 64);
    if (lane == 0) h3[(size_t)b * N1 + n] = fmaxf(s + bias[n], 0.f);
  }
}

// ---- FC2 (300->200) + softmax. One block per batch row.
__global__ __launch_bounds__(256) void fc2sm_kernel(const float* __restrict__ h3,
                                                    const float* __restrict__ w,
                                                    const float* __restrict__ bias,
                                                    float* __restrict__ out) {
  __shared__ float sv[N1];
  __shared__ float sl[N2];
  __shared__ float sred;
  const int b = blockIdx.x;
  const int tid = threadIdx.x;
  const float* src = h3 + (size_t)b * N1;
  if (tid < N1) sv[tid] = src[tid];
  if (tid < N1 - 256) sv[256 + tid] = src[256 + tid];
  __syncthreads();
  float e = 0.f;
  if (tid < N2) {
    const float* wr = w + (size_t)tid * N1;
    float s = bias[tid];
    for (int k = 0; k < N1; k += 2) {
      s = fmaf(wr[k], sv[k], s);
      s = fmaf(wr[k + 1], sv[k + 1], s);
    }
    sl[tid] = s;
  }
  __syncthreads();
  if (tid < 64) {
    float m = -INFINITY;
    for (int i = tid; i < N2; i += 64) m = fmaxf(m, sl[i]);
#pragma unroll
    for (int off = 32; off > 0; off >>= 1) m = fmaxf(m, __shfl_xor(m, off, 64));
    if (tid == 0) sred = m;
  }
  __syncthreads();
  const float mx = sred;
  if (tid < N2) {
    e = expf(sl[tid] - mx);
    sl[tid] = e;
  }
  __syncthreads();
  if (tid < 64) {
    float s = 0.f;
    for (int i = tid; i < N2; i += 64) s += sl[i];
#pragma unroll
    for (int off = 32; off > 0; off >>= 1) s += __shfl_xor(s, off, 64);
    if (tid == 0) sred = s;
  }
  __syncthreads();
  if (tid < N2) out[(size_t)b * N2 + tid] = e / sred;
}

}  // namespace

extern "C" void kernel_launch(void* const* d_in, const int* in_sizes, int n_in,
                              void* d_out, int out_size, void* d_ws, size_t ws_size,
                              hipStream_t stream) {
  const float* x     = (const float*)d_in[0];
  const float* w1    = (const float*)d_in[1];
  const float* b1    = (const float*)d_in[2];
  const float* w2    = (const float*)d_in[3];
  const float* b2    = (const float*)d_in[4];
  const float* fc1_w = (const float*)d_in[5];
  const float* fc1_b = (const float*)d_in[6];
  const float* fc2_w = (const float*)d_in[7];
  const float* fc2_b = (const float*)d_in[8];
  float* out = (float*)d_out;

  float* ws     = (float*)d_ws;
  float* w1t    = ws;                                  // 2,052,864 f
  float* w2t    = w1t + (size_t)O1 * P1 * HW1;         //   599,040 f
  float* h1     = w2t + (size_t)O2 * P2 * HW2;         // 4,866,048 f
  float* h2     = h1 + (size_t)BATCH * O1 * HW1;       //   532,480 f
  float* pooled = h2 + (size_t)BATCH * O2 * HW2;       //   122,880 f
  float* h3     = pooled + (size_t)BATCH * NPOOL;      //    76,800 f

  wt1_kernel<<<(P1 * HW1 + 255) / 256, 256, 0, stream>>>(w1, w1t);
  wt2_kernel<<<(P2 * HW2 + 255) / 256, 256, 0, stream>>>(w2, w2t);
  lc1_kernel<<<dim3((HW1 + 63) / 64, 16), 256, 0, stream>>>(x, w1t, b1, h1);
  lc2_kernel<<<dim3(HW2, 4), 256, 0, stream>>>(h1, w2t, b2, h2);
  pool_kernel<<<(BATCH * NPOOL + 255) / 256, 256, 0, stream>>>(h2, pooled);
  fc1_kernel<<<BATCH, 256, 0, stream>>>(pooled, fc1_w, fc1_b, h3);
  fc2sm_kernel<<<BATCH, 256, 0, stream>>>(h3, fc2_w, fc2_b, out);
}